// Round 4
// baseline (1077.907 us; speedup 1.0000x reference)
//
#include <hip/hip_runtime.h>
#include <math.h>

// ---------------- problem constants ----------------
constexpr int kB = 4, kT = 6, kN = 512, kC = 8;
constexpr int kH = 64, kF = 16, kE = 32;
constexpr int kKS = 3, kKC = 2, kHOR = 3;
constexpr int kBT = kB * kT;          // 24
constexpr int kRK = kBT * kH;         // 1536
constexpr int L_ENC = 1 + kH + kF;    // 81
constexpr int L_DEC = kH + kH + kF;   // 144
constexpr int PL_ENC = 96;            // enc XH layout: [Ht(64)|Xt(1)|pad(15)|feat(16)]
constexpr int PL_DEC = 160;           // dec XH layout: [Hd(64)|Ht(64)|feat(16)|pad(16)]
constexpr int KP_ENC = 3 * PL_ENC;    // 288
constexpr int KP_DEC = 3 * PL_DEC;    // 480
constexpr float kALPHA = 3.0f;

typedef unsigned short ushortT;
typedef short short8 __attribute__((ext_vector_type(8)));
typedef float f32x4 __attribute__((ext_vector_type(4)));

__device__ __forceinline__ float sigm(float x) { return 1.0f / (1.0f + __expf(-x)); }

__device__ __forceinline__ ushortT f2bf(float f) {
    union { float f; unsigned int u; } v; v.f = f;
    unsigned int r = v.u + 0x7fffu + ((v.u >> 16) & 1u);
    return (ushortT)(r >> 16);
}

__device__ __forceinline__ void fma44(const float4& a, const float4& b, float acc[4][4]) {
    acc[0][0] += a.x*b.x; acc[0][1] += a.x*b.y; acc[0][2] += a.x*b.z; acc[0][3] += a.x*b.w;
    acc[1][0] += a.y*b.x; acc[1][1] += a.y*b.y; acc[1][2] += a.y*b.z; acc[1][3] += a.y*b.w;
    acc[2][0] += a.z*b.x; acc[2][1] += a.z*b.y; acc[2][2] += a.z*b.z; acc[2][3] += a.z*b.w;
    acc[3][0] += a.w*b.x; acc[3][1] += a.w*b.y; acc[3][2] += a.w*b.z; acc[3][3] += a.w*b.w;
}

// ---------------- phase 1: projections ----------------

__global__ __launch_bounds__(256) void k_uvproj_s(
    const float* __restrict__ X, const float* __restrict__ Wu, const float* __restrict__ Wv,
    float* __restrict__ Upr, float* __restrict__ Vpr)
{
    int idx = blockIdx.x * blockDim.x + threadIdx.x;
    if (idx >= kN * kBT * kH) return;
    int h = idx % kH; int bt = (idx / kH) % kBT; int n = idx / (kH * kBT);
    const float* xr = X + ((size_t)bt * kN + n) * kC;
    float u = 0.f, v = 0.f;
#pragma unroll
    for (int c = 0; c < kC; ++c) { float x = xr[c]; u += x * Wu[c*kH + h]; v += x * Wv[c*kH + h]; }
    Upr[(size_t)n * kRK + bt * kH + h] = tanhf(kALPHA * u);
    Vpr[(size_t)n * kRK + bt * kH + h] = tanhf(kALPHA * v);
}

// block-per-bt, LDS-tiled categorical projection
__global__ __launch_bounds__(512) void k_uvproj_c2(
    const float* __restrict__ X, const float* __restrict__ WuC, const float* __restrict__ WvC,
    float* __restrict__ Uc, float* __restrict__ Vc)
{
    __shared__ float Xs[4096];
    __shared__ float Wus[4096], Wvs[4096];
    int bt = blockIdx.x, tid = threadIdx.x;
    for (int i = tid; i < 4096; i += 512) Xs[i] = X[(size_t)bt*4096 + i];
    int c = tid >> 6, h = tid & 63;
    float u = 0.f, v = 0.f;
    for (int n0 = 0; n0 < 512; n0 += 64) {
        __syncthreads();
        for (int i = tid; i < 4096; i += 512) { Wus[i] = WuC[n0*64 + i]; Wvs[i] = WvC[n0*64 + i]; }
        __syncthreads();
#pragma unroll 8
        for (int nn = 0; nn < 64; ++nn) {
            float x = Xs[(n0+nn)*8 + c];
            u += x * Wus[nn*64 + h];
            v += x * Wvs[nn*64 + h];
        }
    }
    Uc[(size_t)bt*512 + c*64 + h] = tanhf(kALPHA * u);
    Vc[(size_t)bt*512 + c*64 + h] = tanhf(kALPHA * v);
}

// Mc[c,d] via split-K (8 chunks) in one block
__global__ __launch_bounds__(512) void k_mc2(
    const float* __restrict__ Uc, const float* __restrict__ Vc, float* __restrict__ Mc)
{
    __shared__ float red[512];
    int tid = threadIdx.x;
    int cd = tid & 63, kc = tid >> 6;
    int c = cd >> 3, d = cd & 7;
    float s = 0.f;
    for (int q = kc*192; q < kc*192 + 192; ++q) {
        int bt = q >> 6, h = q & 63;
        s += Uc[(size_t)bt*512 + c*64 + h] * Vc[(size_t)bt*512 + d*64 + h];
    }
    red[tid] = s; __syncthreads();
    for (int st = 256; st >= 64; st >>= 1) { if (tid < st) red[tid] += red[tid + st]; __syncthreads(); }
    if (tid < 64) Mc[tid] = red[tid];
}

// nfS[i] = [rowsum(A_i), 1.0]  (softmax rows sum to 1)
__global__ __launch_bounds__(256) void k_nfa(const float* __restrict__ A, float* __restrict__ nf)
{
    int i = blockIdx.x, tid = threadIdx.x;
    __shared__ float sa[256];
    float a = 0.f;
    for (int j = tid; j < kN; j += 256) a += A[(size_t)i*kN + j];
    sa[tid] = a; __syncthreads();
    for (int s = 128; s > 0; s >>= 1) { if (tid < s) sa[tid] += sa[tid+s]; __syncthreads(); }
    if (!tid) { nf[i*2] = sa[0]; nf[i*2+1] = 1.0f; }
}

// fused: P row = softmax(relu(M-M^T)) ; An[i] = A_i . nf ; Pn[i] = P_i . nf
__global__ __launch_bounds__(256) void k_softmax_anpn(
    const float* __restrict__ M, const float* __restrict__ A, const float* __restrict__ nf,
    float* __restrict__ P, float* __restrict__ An, float* __restrict__ Pn)
{
    int i = blockIdx.x, tid = threadIdx.x;
    __shared__ float s0[256], s1[256], s2[256], s3[256], s4[256];
    float mx = -1e30f;
    for (int j = tid; j < kN; j += 256)
        mx = fmaxf(mx, fmaxf(M[(size_t)i*kN + j] - M[(size_t)j*kN + i], 0.f));
    s0[tid] = mx; __syncthreads();
    for (int s = 128; s > 0; s >>= 1) { if (tid < s) s0[tid] = fmaxf(s0[tid], s0[tid+s]); __syncthreads(); }
    mx = s0[0]; __syncthreads();
    float sum=0, pn0=0, pn1=0, an0=0, an1=0;
    for (int j = tid; j < kN; j += 256) {
        float v = fmaxf(M[(size_t)i*kN + j] - M[(size_t)j*kN + i], 0.f);
        float e = __expf(v - mx);
        P[(size_t)i*kN + j] = e;
        float n0 = nf[2*j], n1 = nf[2*j+1];
        float a = A[(size_t)i*kN + j];
        sum += e; pn0 += e*n0; pn1 += e*n1; an0 += a*n0; an1 += a*n1;
    }
    s0[tid]=sum; s1[tid]=pn0; s2[tid]=pn1; s3[tid]=an0; s4[tid]=an1; __syncthreads();
    for (int s = 128; s > 0; s >>= 1) {
        if (tid < s) { s0[tid]+=s0[tid+s]; s1[tid]+=s1[tid+s]; s2[tid]+=s2[tid+s]; s3[tid]+=s3[tid+s]; s4[tid]+=s4[tid+s]; }
        __syncthreads();
    }
    float inv = 1.f / s0[0];
    if (!tid) { Pn[i*2] = s1[0]*inv; Pn[i*2+1] = s2[0]*inv; An[i*2] = s3[0]; An[i*2+1] = s4[0]; }
    __syncthreads();
    for (int j = tid; j < kN; j += 256) P[(size_t)i*kN + j] *= inv;
}

__global__ __launch_bounds__(256) void k_mlp1cat(
    const float* __restrict__ An, const float* __restrict__ Pn,
    const float* __restrict__ w1, const float* __restrict__ b1, int ia, int ip,
    float* __restrict__ hidAP)
{
    int idx = blockIdx.x * 256 + threadIdx.x;
    if (idx >= 512 * 512) return;
    int col = idx & 511, i = idx >> 9;
    float v;
    if (col < 256) {
        const float* w = w1 + (size_t)ia * 512; const float* b = b1 + (size_t)ia * 256;
        v = An[i*2]*w[col] + An[i*2+1]*w[256 + col] + b[col];
    } else {
        int o = col - 256;
        const float* w = w1 + (size_t)ip * 512; const float* b = b1 + (size_t)ip * 256;
        v = Pn[i*2]*w[o] + Pn[i*2+1]*w[256 + o] + b[o];
    }
    hidAP[idx] = fmaxf(v, 0.f);
}

__global__ __launch_bounds__(256) void k_prep_w2t(
    const float* __restrict__ w2, float* __restrict__ w2tK, float* __restrict__ w2tV)
{
    int idx = blockIdx.x * 256 + threadIdx.x;
    if (idx >= 256 * 512) return;
    int kk = idx & 511, n = idx >> 9;
    int j = kk >> 8, k = kk & 255;
    w2tK[idx] = w2[(size_t)(0 + j)*65536 + k*256 + n];
    w2tV[idx] = w2[(size_t)(2 + j)*65536 + k*256 + n];
}

// ---------------- generic split-K f32 NT GEMM ----------------
__global__ __launch_bounds__(256) void k_gemm_ntsk(
    const float* __restrict__ A, const float* __restrict__ B, float* __restrict__ part,
    int M, int N, int K, int skl)
{
    __shared__ __align__(16) float sA[32][68];
    __shared__ __align__(16) float sB[32][68];
    int tid = threadIdx.x, tx = tid & 15, ty = tid >> 4;
    int j0 = blockIdx.x * 64, i0 = blockIdx.y * 64;
    int kb = blockIdx.z * skl;
    float acc[4][4] = {};
    for (int k0 = kb; k0 < kb + skl; k0 += 32) {
#pragma unroll
        for (int it = 0; it < 2; ++it) {
            int q = tid + it * 256;
            int row = q >> 3, ks = (q & 7) * 4;
            float4 va = *(const float4*)&A[(size_t)(i0 + row)*K + k0 + ks];
            float4 vb = *(const float4*)&B[(size_t)(j0 + row)*K + k0 + ks];
            sA[ks+0][row] = va.x; sA[ks+1][row] = va.y; sA[ks+2][row] = va.z; sA[ks+3][row] = va.w;
            sB[ks+0][row] = vb.x; sB[ks+1][row] = vb.y; sB[ks+2][row] = vb.z; sB[ks+3][row] = vb.w;
        }
        __syncthreads();
#pragma unroll
        for (int kk = 0; kk < 32; ++kk) {
            float4 a = *(const float4*)&sA[kk][ty*4];
            float4 b = *(const float4*)&sB[kk][tx*4];
            fma44(a, b, acc);
        }
        __syncthreads();
    }
    float* dst = part + (size_t)blockIdx.z * M * N;
#pragma unroll
    for (int i = 0; i < 4; ++i)
#pragma unroll
        for (int j = 0; j < 4; ++j)
            dst[(size_t)(i0 + ty*4 + i)*N + j0 + tx*4 + j] = acc[i][j];
}

__global__ __launch_bounds__(256) void k_redep(
    const float* __restrict__ part, int SK, int total, int N,
    float* __restrict__ C, int mode,
    const float* __restrict__ p1, const float* __restrict__ p2)
{
    int idx = blockIdx.x * 256 + threadIdx.x;
    if (idx >= total) return;
    float s = 0.f;
    for (int k = 0; k < SK; ++k) s += part[(size_t)k*total + idx];
    if (mode == 1) { float a = sigm(s); s = a*p1[idx] + (1.f - a)*p2[idx]; }
    else if (mode == 2) { int col = idx % N; s += p1[col] + p2[col]; }
    C[idx] = s;
}

// ---------------- categorical fused MLP chain ----------------
__global__ __launch_bounds__(256) void k_catmlp2(
    const float* __restrict__ Mc, const float* __restrict__ Ac,
    const float* __restrict__ w1, const float* __restrict__ b1,
    const float* __restrict__ w2, const float* __restrict__ b2,
    float* __restrict__ keyval)
{
    __shared__ float Pcs[64], rsA[8], Ans[16], Pns[16];
    __shared__ float hA[8][256], hP[8][256];
    int tid = threadIdx.x;
    int kv = blockIdx.x, c0 = blockIdx.y * 64;
    int qa = kv*2, qp = kv*2 + 1;
    if (tid < 8) {
        int i = tid;
        float row[8]; float mx = -1e30f;
#pragma unroll
        for (int j = 0; j < 8; ++j) { float v = fmaxf(Mc[i*8+j] - Mc[j*8+i], 0.f); row[j] = v; mx = fmaxf(mx, v); }
        float s = 0.f;
#pragma unroll
        for (int j = 0; j < 8; ++j) { row[j] = __expf(row[j] - mx); s += row[j]; }
        float inv = 1.f / s;
#pragma unroll
        for (int j = 0; j < 8; ++j) Pcs[i*8+j] = row[j] * inv;
        float a = 0.f;
#pragma unroll
        for (int j = 0; j < 8; ++j) a += Ac[i*8+j];
        rsA[i] = a;
    }
    __syncthreads();
    if (tid < 16) {
        int i = tid >> 1, comp = tid & 1;
        float an = 0.f, pn = 0.f;
#pragma unroll
        for (int j = 0; j < 8; ++j) {
            float nfj = comp ? 1.f : rsA[j];
            an += Ac[i*8+j] * nfj; pn += Pcs[i*8+j] * nfj;
        }
        Ans[i*2+comp] = an; Pns[i*2+comp] = pn;
    }
    __syncthreads();
    for (int e = tid; e < 2048; e += 256) {
        int i = e >> 8, o = e & 255;
        hA[i][o] = fmaxf(Ans[i*2]*w1[qa*512 + o] + Ans[i*2+1]*w1[qa*512 + 256 + o] + b1[qa*256 + o], 0.f);
        hP[i][o] = fmaxf(Pns[i*2]*w1[qp*512 + o] + Pns[i*2+1]*w1[qp*512 + 256 + o] + b1[qp*256 + o], 0.f);
    }
    __syncthreads();
    for (int e = tid; e < 512; e += 256) {
        int i = e >> 6, oc = c0 + (e & 63);
        float s = b2[qa*256 + oc] + b2[qp*256 + oc];
        for (int k = 0; k < 256; ++k)
            s += hA[i][k]*w2[(size_t)qa*65536 + k*256 + oc] + hP[i][k]*w2[(size_t)qp*65536 + k*256 + oc];
        keyval[(size_t)kv*2048 + i*256 + oc] = s;
    }
}

__global__ void k_gcfuse2(const float* __restrict__ keyval, const float* __restrict__ Mc,
                          const float* __restrict__ Ac, float* __restrict__ GcF)
{
    __shared__ float Pcs[64];
    int t = threadIdx.x; if (t >= 64) return;
    if (t < 8) {
        int i = t;
        float row[8]; float mx = -1e30f;
#pragma unroll
        for (int j = 0; j < 8; ++j) { float v = fmaxf(Mc[i*8+j] - Mc[j*8+i], 0.f); row[j] = v; mx = fmaxf(mx, v); }
        float s = 0.f;
#pragma unroll
        for (int j = 0; j < 8; ++j) { row[j] = __expf(row[j] - mx); s += row[j]; }
        float inv = 1.f / s;
#pragma unroll
        for (int j = 0; j < 8; ++j) Pcs[i*8+j] = row[j] * inv;
    }
    __syncthreads();
    int c = t >> 3, d = t & 7;
    const float* key = keyval;
    const float* val = keyval + 2048;
    float s = 0.f;
    for (int k = 0; k < 256; ++k) s += key[c*256 + k] * val[d*256 + k];
    float a = sigm(s);
    GcF[c*8 + d] = a*Ac[c*8 + d] + (1.f - a)*Pcs[c*8 + d];
}

// ---------------- bf16 preps ----------------

__global__ void k_transp(const float* __restrict__ G, ushortT* __restrict__ Gt)
{
    __shared__ float tile[32][33];
    int bx = blockIdx.x * 32, by = blockIdx.y * 32;
    int x = threadIdx.x, y0 = threadIdx.y;
    for (int yy = y0; yy < 32; yy += 8) tile[yy][x] = G[(size_t)(by+yy)*kN + bx + x];
    __syncthreads();
    for (int yy = y0; yy < 32; yy += 8) Gt[(size_t)(bx+yy)*kN + by + x] = f2bf(tile[x][yy]);
}

// WT[o][kk*PL + p] = W[((kk*2+j)*L + lorig(p)) * outW + oo]; mode 1 = enc layout remap
__global__ __launch_bounds__(256) void k_prep_wt(
    const float* __restrict__ W, ushortT* __restrict__ WT,
    int L, int PL, int KP, int outW, int mode)
{
    int idx = blockIdx.x * blockDim.x + threadIdx.x;
    if (idx >= 2 * outW * KP) return;
    int qp = idx % KP, o = idx / KP;
    int kk = qp / PL, l = qp - kk * PL;
    int lo;
    if (mode == 1) lo = (l < 64) ? l + 1 : (l == 64) ? 0 : (l < 80) ? L : (l - 15);
    else lo = l;
    int j = o / outW, oo = o - j * outW;
    float v = (lo < L) ? W[(size_t)((kk*2 + j)*L + lo) * outW + oo] : 0.f;
    WT[idx] = f2bf(v);
}

// Gst2 = 2 * Gst @ Gst - I (bf16)
__global__ __launch_bounds__(256) void k_cheby_mfma(
    const ushortT* __restrict__ Gst, ushortT* __restrict__ Gst2)
{
    __shared__ short sA[128][40];
    __shared__ short sB[128][40];
    int tid = threadIdx.x;
    int m0 = blockIdx.y * 128, j0 = blockIdx.x * 128;
    int w = tid >> 6, lane = tid & 63, wr = w >> 1, wc = w & 1;
    f32x4 acc[4][4];
#pragma unroll
    for (int i = 0; i < 4; ++i)
#pragma unroll
        for (int j = 0; j < 4; ++j) acc[i][j] = (f32x4){0.f, 0.f, 0.f, 0.f};
    for (int k0 = 0; k0 < kN; k0 += 32) {
        {
            int row = tid >> 1, lc = (tid & 1) * 16;
            const ushortT* p = Gst + (size_t)(m0 + row)*kN + k0 + lc;
            *(short8*)&sA[row][lc]     = *(const short8*)p;
            *(short8*)&sA[row][lc + 8] = *(const short8*)(p + 8);
        }
        {
            int kr = tid & 31, jc = (tid >> 5) * 8;
#pragma unroll
            for (int rep = 0; rep < 2; ++rep) {
                short8 v = *(const short8*)(Gst + (size_t)(k0 + kr)*kN + j0 + jc + rep*64);
#pragma unroll
                for (int i = 0; i < 8; ++i) sB[jc + rep*64 + i][kr] = v[i];
            }
        }
        __syncthreads();
        short8 af[4], bfr[4];
#pragma unroll
        for (int mi = 0; mi < 4; ++mi)
            af[mi] = *(const short8*)&sA[wr*64 + mi*16 + (lane & 15)][(lane >> 4) * 8];
#pragma unroll
        for (int ni = 0; ni < 4; ++ni)
            bfr[ni] = *(const short8*)&sB[wc*64 + ni*16 + (lane & 15)][(lane >> 4) * 8];
#pragma unroll
        for (int mi = 0; mi < 4; ++mi)
#pragma unroll
            for (int ni = 0; ni < 4; ++ni)
                acc[mi][ni] = __builtin_amdgcn_mfma_f32_16x16x32_bf16(af[mi], bfr[ni], acc[mi][ni], 0, 0, 0);
        __syncthreads();
    }
#pragma unroll
    for (int mi = 0; mi < 4; ++mi) {
#pragma unroll
        for (int ni = 0; ni < 4; ++ni) {
            int row0 = m0 + wr*64 + mi*16 + (lane >> 4) * 4;
            int col  = j0 + wc*64 + ni*16 + (lane & 15);
#pragma unroll
            for (int q = 0; q < 4; ++q) {
                int row = row0 + q;
                Gst2[(size_t)row*kN + col] = f2bf(2.f*acc[mi][ni][q] - (row == col ? 1.f : 0.f));
            }
        }
    }
}

// ---------------- mapped t1: Y cols (c*PL + OFF + [0,ACTW)) only ----------------
template<int CLP, int PL, int ACTW, int OFF>
__global__ __launch_bounds__(256) void k_t1m(
    const ushortT* __restrict__ Gst, const ushortT* __restrict__ Xin, ushortT* __restrict__ Yout)
{
    __shared__ short sA[128][40];
    __shared__ short sB[128][40];
    int tid = threadIdx.x;
    int ki = blockIdx.z >> 2, b = blockIdx.z & 3;
    const ushortT* A = Gst + (size_t)ki * kN * kN;
    const ushortT* B = Xin + (size_t)b * kN * CLP;
    ushortT* C = Yout + (size_t)(ki*4 + b) * kN * CLP;
    int m0 = blockIdx.y * 128, j0 = blockIdx.x * 128;
    int w = tid >> 6, lane = tid & 63, wr = w >> 1, wc = w & 1;
    f32x4 acc[4][4];
#pragma unroll
    for (int i = 0; i < 4; ++i)
#pragma unroll
        for (int j = 0; j < 4; ++j) acc[i][j] = (f32x4){0.f, 0.f, 0.f, 0.f};

    for (int k0 = 0; k0 < kN; k0 += 32) {
        {
            int row = tid >> 1, lc = (tid & 1) * 16;
            const ushortT* p = A + (size_t)(m0 + row)*kN + k0 + lc;
            *(short8*)&sA[row][lc]     = *(const short8*)p;
            *(short8*)&sA[row][lc + 8] = *(const short8*)(p + 8);
        }
        {
            int kr = tid & 31, jc = (tid >> 5) * 8;
#pragma unroll
            for (int rep = 0; rep < 2; ++rep) {
                int j = j0 + jc + rep*64;
                int cg = j / ACTW;
                int col = cg*PL + OFF + (j - cg*ACTW);
                short8 v = *(const short8*)(B + (size_t)(k0 + kr)*CLP + col);
#pragma unroll
                for (int i = 0; i < 8; ++i) sB[jc + rep*64 + i][kr] = v[i];
            }
        }
        __syncthreads();
        short8 af[4], bfr[4];
#pragma unroll
        for (int mi = 0; mi < 4; ++mi)
            af[mi] = *(const short8*)&sA[wr*64 + mi*16 + (lane & 15)][(lane >> 4) * 8];
#pragma unroll
        for (int ni = 0; ni < 4; ++ni)
            bfr[ni] = *(const short8*)&sB[wc*64 + ni*16 + (lane & 15)][(lane >> 4) * 8];
#pragma unroll
        for (int mi = 0; mi < 4; ++mi)
#pragma unroll
            for (int ni = 0; ni < 4; ++ni)
                acc[mi][ni] = __builtin_amdgcn_mfma_f32_16x16x32_bf16(af[mi], bfr[ni], acc[mi][ni], 0, 0, 0);
        __syncthreads();
    }
#pragma unroll
    for (int mi = 0; mi < 4; ++mi) {
#pragma unroll
        for (int ni = 0; ni < 4; ++ni) {
            int row = m0 + wr*64 + mi*16 + (lane >> 4) * 4;
            int fj = j0 + wc*64 + ni*16;
            int cg = fj / ACTW;
            int col = cg*PL + OFF + (fj - cg*ACTW) + (lane & 15);
#pragma unroll
            for (int q = 0; q < 4; ++q)
                C[(size_t)(row + q)*CLP + col] = f2bf(acc[mi][ni][q]);
        }
    }
}

// ---------------- fused gates GEMM + epilogue ----------------
// C[16384 x 256] = gather(XH,Yb) @ WT^T ; then Gc-mix + sigmoid -> upd, reset*Ht into XH
template<int PL, int KP, int XOFF>
__global__ __launch_bounds__(256) void k_gates_f(
    ushortT* __restrict__ XH, const ushortT* __restrict__ Yb,
    const ushortT* __restrict__ WT, const float* __restrict__ GcM,
    const float* __restrict__ gb, const float* __restrict__ Ht,
    float* __restrict__ upd)
{
    __shared__ short sA[64][40];
    __shared__ short sB[256][40];
    __shared__ float sEp[32][260];
    __shared__ float GcS[64], gbS[128];
    int tid = threadIdx.x;
    int r0 = blockIdx.x * 64;
    int b = r0 >> 12, rr = r0 & 4095;
    const ushortT* src0 = XH + (size_t)r0 * PL;
    const ushortT* src1 = Yb + ((size_t)b * 4096 + rr) * PL;
    const ushortT* src2 = Yb + ((size_t)(4 + b) * 4096 + rr) * PL;
    if (tid < 64) GcS[tid] = GcM[tid];
    if (tid >= 64 && tid < 192) gbS[tid - 64] = gb[tid - 64];
    int w = tid >> 6, lane = tid & 63;
    f32x4 acc[4][4];
#pragma unroll
    for (int i = 0; i < 4; ++i)
#pragma unroll
        for (int j = 0; j < 4; ++j) acc[i][j] = (f32x4){0.f, 0.f, 0.f, 0.f};

    for (int k0 = 0; k0 < KP; k0 += 32) {
        int kk = k0 / PL, l0 = k0 - kk * PL;
        const ushortT* Ap = (kk == 0) ? src0 : (kk == 1) ? src1 : src2;
        {
            int row = tid >> 2, lc = (tid & 3) * 8;
            *(short8*)&sA[row][lc] = *(const short8*)(Ap + (size_t)row*PL + l0 + lc);
        }
        {
            const ushortT* p = WT + (size_t)tid*KP + k0;
            *(short8*)&sB[tid][0]  = *(const short8*)(p);
            *(short8*)&sB[tid][8]  = *(const short8*)(p + 8);
            *(short8*)&sB[tid][16] = *(const short8*)(p + 16);
            *(short8*)&sB[tid][24] = *(const short8*)(p + 24);
        }
        __syncthreads();
        short8 af[4], bfr[4];
#pragma unroll
        for (int mi = 0; mi < 4; ++mi)
            af[mi] = *(const short8*)&sA[mi*16 + (lane & 15)][(lane >> 4) * 8];
#pragma unroll
        for (int ni = 0; ni < 4; ++ni)
            bfr[ni] = *(const short8*)&sB[w*64 + ni*16 + (lane & 15)][(lane >> 4) * 8];
#pragma unroll
        for (int mi = 0; mi < 4; ++mi)
#pragma unroll
            for (int ni = 0; ni < 4; ++ni)
                acc[mi][ni] = __builtin_amdgcn_mfma_f32_16x16x32_bf16(af[mi], bfr[ni], acc[mi][ni], 0, 0, 0);
        __syncthreads();
    }
    // epilogue: 2 chunks of 32 rows
    for (int chunk = 0; chunk < 2; ++chunk) {
#pragma unroll
        for (int mi2 = 0; mi2 < 2; ++mi2) {
            int mi = chunk*2 + mi2;
#pragma unroll
            for (int ni = 0; ni < 4; ++ni)
#pragma unroll
                for (int q = 0; q < 4; ++q)
                    sEp[mi2*16 + (lane >> 4)*4 + q][w*64 + ni*16 + (lane & 15)] = acc[mi][ni][q];
        }
        __syncthreads();
        for (int it = 0; it < 16; ++it) {
            int idx = it*256 + tid;
            int o = idx & 127, rloc = idx >> 7;
            int r = r0 + chunk*32 + rloc;
            int d = r & 7, bb = rloc & ~7;
            float pre = sEp[rloc][o] + gbS[o];
#pragma unroll
            for (int c = 0; c < 8; ++c) pre += GcS[c*8 + d] * sEp[bb + c][128 + o];
            float g = sigm(pre);
            if (o < 64) upd[(size_t)r*64 + o] = g;
            else {
                int h = o - 64;
                XH[(size_t)r*PL + XOFF + h] = f2bf(g * Ht[(size_t)r*64 + h]);
            }
        }
        __syncthreads();
    }
}

// ---------------- fused cand GEMM + epilogue ----------------
template<int PL, int KP>
__global__ __launch_bounds__(256) void k_cand_f(
    const ushortT* __restrict__ XH, const ushortT* __restrict__ Yb,
    const ushortT* __restrict__ WT, const float* __restrict__ GcM,
    const float* __restrict__ cb, const float* __restrict__ upd,
    float* __restrict__ Ht)
{
    __shared__ short sA[64][40];
    __shared__ short sB[128][40];
    __shared__ float sEp[64][132];
    __shared__ float GcS[64], cbS[64];
    int tid = threadIdx.x;
    int r0 = blockIdx.x * 64;
    int b = r0 >> 12, rr = r0 & 4095;
    const ushortT* src0 = XH + (size_t)r0 * PL;
    const ushortT* src1 = Yb + ((size_t)b * 4096 + rr) * PL;
    const ushortT* src2 = Yb + ((size_t)(4 + b) * 4096 + rr) * PL;
    if (tid < 64) GcS[tid] = GcM[tid];
    if (tid >= 64 && tid < 128) cbS[tid - 64] = cb[tid - 64];
    int w = tid >> 6, lane = tid & 63;
    f32x4 acc[4][2];
#pragma unroll
    for (int i = 0; i < 4; ++i)
#pragma unroll
        for (int j = 0; j < 2; ++j) acc[i][j] = (f32x4){0.f, 0.f, 0.f, 0.f};

    for (int k0 = 0; k0 < KP; k0 += 32) {
        int kk = k0 / PL, l0 = k0 - kk * PL;
        const ushortT* Ap = (kk == 0) ? src0 : (kk == 1) ? src1 : src2;
        {
            int row = tid >> 2, lc = (tid & 3) * 8;
            *(short8*)&sA[row][lc] = *(const short8*)(Ap + (size_t)row*PL + l0 + lc);
        }
        {
            int col = tid >> 1, seg = (tid & 1) * 16;
            const ushortT* p = WT + (size_t)col*KP + k0 + seg;
            *(short8*)&sB[col][seg]     = *(const short8*)p;
            *(short8*)&sB[col][seg + 8] = *(const short8*)(p + 8);
        }
        __syncthreads();
        short8 af[4], bfr[2];
#pragma unroll
        for (int mi = 0; mi < 4; ++mi)
            af[mi] = *(const short8*)&sA[mi*16 + (lane & 15)][(lane >> 4) * 8];
#pragma unroll
        for (int ni = 0; ni < 2; ++ni)
            bfr[ni] = *(const short8*)&sB[w*32 + ni*16 + (lane & 15)][(lane >> 4) * 8];
#pragma unroll
        for (int mi = 0; mi < 4; ++mi)
#pragma unroll
            for (int ni = 0; ni < 2; ++ni)
                acc[mi][ni] = __builtin_amdgcn_mfma_f32_16x16x32_bf16(af[mi], bfr[ni], acc[mi][ni], 0, 0, 0);
        __syncthreads();
    }
#pragma unroll
    for (int mi = 0; mi < 4; ++mi)
#pragma unroll
        for (int ni = 0; ni < 2; ++ni)
#pragma unroll
            for (int q = 0; q < 4; ++q)
                sEp[mi*16 + (lane >> 4)*4 + q][w*32 + ni*16 + (lane & 15)] = acc[mi][ni][q];
    __syncthreads();
    for (int it = 0; it < 16; ++it) {
        int idx = it*256 + tid;
        int o = idx & 63, rloc = idx >> 6;
        int r = r0 + rloc;
        int d = r & 7, bb = rloc & ~7;
        float pre = sEp[rloc][o] + cbS[o];
#pragma unroll
        for (int c = 0; c < 8; ++c) pre += GcS[c*8 + d] * sEp[bb + c][64 + o];
        float cv = tanhf(pre);
        float u = upd[(size_t)r*64 + o];
        float h0 = Ht[(size_t)r*64 + o];
        Ht[(size_t)r*64 + o] = (1.f - u)*h0 + u*cv;
    }
}

// ---------------- builds / outmlp ----------------

// enc XH layout: [Ht(0..63) | Xt(64) | pad(65..79) | feat(80..95)]
__global__ __launch_bounds__(256) void k_build_enc(
    const float* __restrict__ X, int t, const float* __restrict__ Ht,
    const float* __restrict__ featr, ushortT* __restrict__ XH)
{
    int idx = blockIdx.x * blockDim.x + threadIdx.x;
    if (idx >= 16384 * PL_ENC) return;
    int l = idx % PL_ENC; int r = idx / PL_ENC;
    int c = r & 7; int m = (r >> 3) & 511; int b = r >> 12;
    float v;
    if (l < 64)            v = Ht[(size_t)r*kH + l];
    else if (l == 64)      v = X[(((size_t)b*kT + t)*kN + m)*kC + c];
    else if (l < 80)       v = 0.f;
    else                   v = featr[m*kF + (l - 80)];
    XH[idx] = f2bf(v);
}

// dec XH layout: [Hd(0..63) | Ht(64..127) | feat(128..143) | pad]
__global__ __launch_bounds__(256) void k_build_dec(
    const float* __restrict__ Ht, const float* __restrict__ featr, ushortT* __restrict__ XH)
{
    int idx = blockIdx.x * blockDim.x + threadIdx.x;
    if (idx >= 16384 * PL_DEC) return;
    int l = idx % PL_DEC; int r = idx / PL_DEC;
    int m = (r >> 3) & 511;
    float v;
    if (l < kH)            v = Ht[(size_t)r*kH + l];
    else if (l < 2*kH)     v = Ht[(size_t)r*kH + l - kH];
    else if (l < L_DEC)    v = featr[m*kF + l - 2*kH];
    else                   v = 0.f;
    XH[idx] = f2bf(v);
}

__global__ __launch_bounds__(256) void k_outmlp(
    const float* __restrict__ Hd, const float* __restrict__ w1, const float* __restrict__ b1,
    const float* __restrict__ w2, const float* __restrict__ b2, float* __restrict__ out, int hz)
{
    int idx = blockIdx.x * blockDim.x + threadIdx.x;
    if (idx >= kB*kN*kC) return;
    int c = idx % kC; int m = (idx / kC) % kN; int b = idx / (kC*kN);
    const float* h = Hd + (size_t)idx * kH;
    float hreg[kH];
#pragma unroll
    for (int k = 0; k < kH; ++k) hreg[k] = h[k];
    float acc = b2[0];
    for (int e = 0; e < kE; ++e) {
        float s = b1[e];
#pragma unroll
        for (int k = 0; k < kH; ++k) s += hreg[k] * w1[k*kE + e];
        acc += fmaxf(s, 0.f) * w2[e];
    }
    out[((size_t)(b*kHOR + hz)*kN + m)*kC + c] = acc;
}

// ---------------- host ----------------
extern "C" void kernel_launch(void* const* d_in, const int* in_sizes, int n_in,
                              void* d_out, int out_size, void* d_ws, size_t ws_size,
                              hipStream_t stream)
{
    (void)in_sizes; (void)n_in; (void)out_size; (void)ws_size;
    const float* X      = (const float*)d_in[0];
    const float* As     = (const float*)d_in[1];
    const float* Ac     = (const float*)d_in[2];
    const float* featr  = (const float*)d_in[3];
    const float* WuS    = (const float*)d_in[4];
    const float* WvS    = (const float*)d_in[5];
    const float* WuC    = (const float*)d_in[6];
    const float* WvC    = (const float*)d_in[7];
    const float* mfS_w1 = (const float*)d_in[8];
    const float* mfS_b1 = (const float*)d_in[9];
    const float* mfS_w2 = (const float*)d_in[10];
    const float* mfS_b2 = (const float*)d_in[11];
    const float* mfC_w1 = (const float*)d_in[12];
    const float* mfC_b1 = (const float*)d_in[13];
    const float* mfC_w2 = (const float*)d_in[14];
    const float* mfC_b2 = (const float*)d_in[15];
    const float* enc_gW = (const float*)d_in[16];
    const float* enc_gb = (const float*)d_in[17];
    const float* enc_cW = (const float*)d_in[18];
    const float* enc_cb = (const float*)d_in[19];
    const float* dec_gW = (const float*)d_in[20];
    const float* dec_gb = (const float*)d_in[21];
    const float* dec_cW = (const float*)d_in[22];
    const float* dec_cb = (const float*)d_in[23];
    const float* out_w1 = (const float*)d_in[24];
    const float* out_b1 = (const float*)d_in[25];
    const float* out_w2 = (const float*)d_in[26];
    const float* out_b2 = (const float*)d_in[27];
    float* out = (float*)d_out;
    float* ws = (float*)d_ws;

    // ---- arena (floats) ----
    float* Ht     = ws;                      // 1,048,576
    float* updb   = Ht + 1048576;            // 1,048,576
    float* Gg     = updb + 1048576;          // 4,194,304 (phase1 aliases)
    float* Gs     = Gg + 4194304;            // 262,144
    float* smallf = Gs + 262144;             // 8,192
    float* nfS = smallf;                     // 1024
    float* AnS = nfS + 1024;
    float* PnS = AnS + 1024;
    float* McB = PnS + 1024;
    float* GcF = McB + 64;
    float* kvC = GcF + 64;                   // 4096
    ushortT* XHb  = (ushortT*)(smallf + 8192);   // 16384*160 = 2,621,440
    ushortT* Yb   = XHb + 2621440;               // 5,242,880
    ushortT* GstB = Yb + 5242880;                // 524,288 (Gst + Gst2)
    ushortT* WTg_e = GstB + 524288;              // 73,728
    ushortT* WTc_e = WTg_e + 73728;              // 36,864
    ushortT* WTg_d = WTc_e + 36864;              // 122,880
    ushortT* WTc_d = WTg_d + 122880;             // 61,440
    // phase-1 aliases inside Gg
    float* Upr   = Gg;                       // 786,432
    float* Vpr   = Upr + 786432;             // 786,432
    float* part  = Vpr + 786432;             // 1,048,576
    float* Ms    = part + 1048576;           // 262,144
    float* Ps    = Ms + 262144;              // 262,144
    float* hidAP = Ps + 262144;              // 262,144
    float* keyS  = hidAP + 262144;           // 131,072
    float* valS  = keyS + 131072;            // 131,072
    float* w2tK  = valS + 131072;            // 131,072
    float* w2tV  = w2tK + 131072;            // 131,072
    float* Uc    = w2tV + 131072;            // 12,288
    float* Vc    = Uc + 12288;               // 12,288

    constexpr int CLP_ENC = kC * PL_ENC;   // 768
    constexpr int CLP_DEC = kC * PL_DEC;   // 1280

    hipMemsetAsync(Ht, 0, (size_t)16384 * kH * sizeof(float), stream);

    // ---- weight preps ----
    k_prep_wt<<<(2*128*KP_ENC + 255)/256, 256, 0, stream>>>(enc_gW, WTg_e, L_ENC, PL_ENC, KP_ENC, 128, 1);
    k_prep_wt<<<(2*64 *KP_ENC + 255)/256, 256, 0, stream>>>(enc_cW, WTc_e, L_ENC, PL_ENC, KP_ENC, 64, 1);
    k_prep_wt<<<(2*128*KP_DEC + 255)/256, 256, 0, stream>>>(dec_gW, WTg_d, L_DEC, PL_DEC, KP_DEC, 128, 0);
    k_prep_wt<<<(2*64 *KP_DEC + 255)/256, 256, 0, stream>>>(dec_cW, WTc_d, L_DEC, PL_DEC, KP_DEC, 64, 0);
    k_prep_w2t<<<512, 256, 0, stream>>>(mfS_w2, w2tK, w2tV);

    // ---- phase 1: spatial graph ----
    k_uvproj_s<<<(kN*kBT*kH + 255)/256, 256, 0, stream>>>(X, WuS, WvS, Upr, Vpr);
    k_gemm_ntsk<<<dim3(8, 8, 4), 256, 0, stream>>>(Upr, Vpr, part, 512, 512, 1536, 384);
    k_redep<<<1024, 256, 0, stream>>>(part, 4, 262144, 512, Ms, 0, nullptr, nullptr);
    k_nfa<<<kN, 256, 0, stream>>>(As, nfS);
    k_softmax_anpn<<<kN, 256, 0, stream>>>(Ms, As, nfS, Ps, AnS, PnS);
    k_mlp1cat<<<1024, 256, 0, stream>>>(AnS, PnS, mfS_w1, mfS_b1, 0, 1, hidAP);
    k_gemm_ntsk<<<dim3(4, 8, 2), 256, 0, stream>>>(hidAP, w2tK, part, 512, 256, 512, 256);
    k_redep<<<512, 256, 0, stream>>>(part, 2, 131072, 256, keyS, 2, mfS_b2, mfS_b2 + 256);
    k_mlp1cat<<<1024, 256, 0, stream>>>(AnS, PnS, mfS_w1, mfS_b1, 2, 3, hidAP);
    k_gemm_ntsk<<<dim3(4, 8, 2), 256, 0, stream>>>(hidAP, w2tV, part, 512, 256, 512, 256);
    k_redep<<<512, 256, 0, stream>>>(part, 2, 131072, 256, valS, 2, mfS_b2 + 512, mfS_b2 + 768);
    k_gemm_ntsk<<<dim3(8, 8, 2), 256, 0, stream>>>(keyS, valS, part, 512, 512, 256, 128);
    k_redep<<<1024, 256, 0, stream>>>(part, 2, 262144, 512, Gs, 1, As, Ps);
    k_transp<<<dim3(16, 16), dim3(32, 8), 0, stream>>>(Gs, GstB);
    k_cheby_mfma<<<dim3(4, 4), 256, 0, stream>>>(GstB, GstB + 262144);

    // ---- phase 1: categorical graph ----
    k_uvproj_c2<<<kBT, 512, 0, stream>>>(X, WuC, WvC, Uc, Vc);
    k_mc2<<<1, 512, 0, stream>>>(Uc, Vc, McB);
    k_catmlp2<<<dim3(2, 4), 256, 0, stream>>>(McB, Ac, mfC_w1, mfC_b1, mfC_w2, mfC_b2, kvC);
    k_gcfuse2<<<1, 64, 0, stream>>>(kvC, McB, Ac, GcF);

    // ---- encoder ----
    // feat-Y init (static across enc cells): cols c*96 + [80,96)
    bool featDone = false;
    for (int t = 0; t < kT; ++t) {
        k_build_enc<<<(16384*PL_ENC + 255)/256, 256, 0, stream>>>(X, t, Ht, featr, XHb);
        if (!featDone) {
            k_t1m<CLP_ENC, PL_ENC, 16, 80><<<dim3(1, 4, 8), 256, 0, stream>>>(GstB, XHb, Yb);
            featDone = true;
        }
        k_t1m<CLP_ENC, PL_ENC, 80, 0><<<dim3(5, 4, 8), 256, 0, stream>>>(GstB, XHb, Yb);
        k_gates_f<PL_ENC, KP_ENC, 0><<<256, 256, 0, stream>>>(XHb, Yb, WTg_e, GcF, enc_gb, Ht, updb);
        k_t1m<CLP_ENC, PL_ENC, 64, 0><<<dim3(4, 4, 8), 256, 0, stream>>>(GstB, XHb, Yb);
        k_cand_f<PL_ENC, KP_ENC><<<256, 256, 0, stream>>>(XHb, Yb, WTc_e, GcF, enc_cb, updb, Ht);
    }

    // ---- decoder ----
    featDone = false;
    for (int hz = 0; hz < kHOR; ++hz) {
        k_build_dec<<<(16384*PL_DEC + 255)/256, 256, 0, stream>>>(Ht, featr, XHb);
        if (!featDone) {
            k_t1m<CLP_DEC, PL_DEC, 16, 128><<<dim3(1, 4, 8), 256, 0, stream>>>(GstB, XHb, Yb);
            featDone = true;
        }
        k_t1m<CLP_DEC, PL_DEC, 128, 0><<<dim3(8, 4, 8), 256, 0, stream>>>(GstB, XHb, Yb);
        k_gates_f<PL_DEC, KP_DEC, 64><<<256, 256, 0, stream>>>(XHb, Yb, WTg_d, GcF, dec_gb, Ht, updb);
        k_t1m<CLP_DEC, PL_DEC, 64, 64><<<dim3(4, 4, 8), 256, 0, stream>>>(GstB, XHb, Yb);
        k_cand_f<PL_DEC, KP_DEC><<<256, 256, 0, stream>>>(XHb, Yb, WTc_d, GcF, dec_cb, updb, Ht);
        k_outmlp<<<(kB*kN*kC + 255)/256, 256, 0, stream>>>(Ht, out_w1, out_b1, out_w2, out_b2, out, hz);
    }
}